// Round 1
// baseline (154.316 us; speedup 1.0000x reference)
//
#include <hip/hip_runtime.h>
#include <math.h>

// Problem constants (from reference setup)
constexpr int B  = 32;
constexpr int C  = 64;
constexpr int H  = 128;
constexpr int W  = 128;
constexpr int HW = H * W;            // 16384
constexpr int SB = 2 * C * HW;       // per-batch stride in floats = 2,097,152
constexpr float EPS = 1e-5f;

// ---------------------------------------------------------------------------
// Kernel 1: per-(channel, batch) partial sums.
// Each block reduces one 16384-element xr plane and its paired xi plane.
// Outputs 5 floats per (c,b): sum_r, sum_i, sum_rr, sum_ii, sum_ri.
// Deterministic (no atomics): fixed tree reduction.
// ---------------------------------------------------------------------------
__global__ __launch_bounds__(256) void k_partial(const float* __restrict__ x,
                                                 float* __restrict__ part) {
    const int c = blockIdx.x;   // channel
    const int b = blockIdx.y;   // batch
    const float* __restrict__ xr = x + (size_t)b * SB + (size_t)c * HW;
    const float* __restrict__ xi = xr + (size_t)C * HW;
    const int tid = threadIdx.x;

    float sr = 0.f, si = 0.f, srr = 0.f, sii = 0.f, sri = 0.f;

#pragma unroll
    for (int it = 0; it < HW / (256 * 4); ++it) {   // 16 iterations
        const int idx = (it * 256 + tid) * 4;
        const float4 r = *reinterpret_cast<const float4*>(xr + idx);
        const float4 i = *reinterpret_cast<const float4*>(xi + idx);
        sr  += r.x + r.y + r.z + r.w;
        si  += i.x + i.y + i.z + i.w;
        srr += r.x * r.x + r.y * r.y + r.z * r.z + r.w * r.w;
        sii += i.x * i.x + i.y * i.y + i.z * i.z + i.w * i.w;
        sri += r.x * i.x + r.y * i.y + r.z * i.z + r.w * i.w;
    }

    // 64-lane wave reduction
#pragma unroll
    for (int off = 32; off > 0; off >>= 1) {
        sr  += __shfl_down(sr,  off);
        si  += __shfl_down(si,  off);
        srr += __shfl_down(srr, off);
        sii += __shfl_down(sii, off);
        sri += __shfl_down(sri, off);
    }

    __shared__ float smem[4][5];
    const int wave = tid >> 6;
    const int lane = tid & 63;
    if (lane == 0) {
        smem[wave][0] = sr;  smem[wave][1] = si;  smem[wave][2] = srr;
        smem[wave][3] = sii; smem[wave][4] = sri;
    }
    __syncthreads();
    if (tid == 0) {
        float* dst = part + ((size_t)c * B + b) * 5;
#pragma unroll
        for (int k = 0; k < 5; ++k)
            dst[k] = smem[0][k] + smem[1][k] + smem[2][k] + smem[3][k];
    }
}

// ---------------------------------------------------------------------------
// Kernel 2: fold partials per channel, compute whitening coefficients.
// One block, 64 threads (one per channel). Tiny.
// Writes 8 floats per channel: mr, mi, a00, a01, a10, a11, b0, b1.
// Implements the reference math LITERALLY (t = sqrt(tau + 2*delta), and
// s added to all four q entries).
// ---------------------------------------------------------------------------
__global__ __launch_bounds__(64) void k_stats(const float* __restrict__ part,
                                              const float* __restrict__ gamma,
                                              const float* __restrict__ beta,
                                              float* __restrict__ coef) {
    const int c = threadIdx.x;
    float sr = 0.f, si = 0.f, srr = 0.f, sii = 0.f, sri = 0.f;
    const float* p = part + (size_t)c * B * 5;
#pragma unroll
    for (int b = 0; b < B; ++b) {
        sr  += p[b * 5 + 0];
        si  += p[b * 5 + 1];
        srr += p[b * 5 + 2];
        sii += p[b * 5 + 3];
        sri += p[b * 5 + 4];
    }
    const float N    = (float)(B * HW);       // 524288
    const float invN = 1.f / N;
    const float mr   = sr * invN;
    const float mi   = si * invN;
    const float d    = N - 1.f;

    const float covRR = (srr - N * mr * mr) / d;
    const float covII = (sii - N * mi * mi) / d;
    const float covRI = (sri - N * mr * mi) / d;

    const float m00 = covRR + EPS;
    const float m01 = covRI;
    const float m10 = covRI;
    const float m11 = covII + EPS;

    const float tau   = m00 + m11;
    const float delta = m00 * m11 - m01 * m10;
    const float s     = sqrtf(delta);
    const float t     = sqrtf(tau + 2.f * delta);   // reference uses delta here, not s

    const float q00 = (m00 + s) / t;
    const float q01 = (m01 + s) / t;
    const float q10 = (m10 + s) / t;
    const float q11 = (m11 + s) / t;

    const float det    = q00 * q11 - q01 * q10;
    const float invdet = 1.f / det;
    const float v00 =  q11 * invdet;
    const float v01 = -q01 * invdet;
    const float v10 = -q10 * invdet;
    const float v11 =  q00 * invdet;

    const float g00 = gamma[c * 4 + 0];
    const float g01 = gamma[c * 4 + 1];
    const float g10 = gamma[c * 4 + 2];
    const float g11 = gamma[c * 4 + 3];

    const float a00 = g00 * v00 + g01 * v10;
    const float a01 = g00 * v01 + g01 * v11;
    const float a10 = g10 * v00 + g11 * v10;
    const float a11 = g10 * v01 + g11 * v11;

    float* o = coef + c * 8;
    o[0] = mr;  o[1] = mi;
    o[2] = a00; o[3] = a01; o[4] = a10; o[5] = a11;
    o[6] = beta[c * 2 + 0];
    o[7] = beta[c * 2 + 1];
}

// ---------------------------------------------------------------------------
// Kernel 3: elementwise normalize. Grid (HW/1024, B*C). float4 in/out.
// ---------------------------------------------------------------------------
__global__ __launch_bounds__(256) void k_norm(const float* __restrict__ x,
                                              const float* __restrict__ coef,
                                              float* __restrict__ out) {
    const int bc = blockIdx.y;       // 0 .. B*C-1
    const int b  = bc / C;
    const int c  = bc % C;

    const float* co = coef + c * 8;
    const float mr  = co[0], mi  = co[1];
    const float a00 = co[2], a01 = co[3], a10 = co[4], a11 = co[5];
    const float b0  = co[6], b1  = co[7];

    const size_t baseR = (size_t)b * SB + (size_t)c * HW;
    const size_t baseI = baseR + (size_t)C * HW;
    const int idx = (blockIdx.x * 256 + threadIdx.x) * 4;

    const float4 r = *reinterpret_cast<const float4*>(x + baseR + idx);
    const float4 i = *reinterpret_cast<const float4*>(x + baseI + idx);

    float4 yr, yi;
    yr.x = a00 * (r.x - mr) + a01 * (i.x - mi) + b0;
    yr.y = a00 * (r.y - mr) + a01 * (i.y - mi) + b0;
    yr.z = a00 * (r.z - mr) + a01 * (i.z - mi) + b0;
    yr.w = a00 * (r.w - mr) + a01 * (i.w - mi) + b0;
    yi.x = a10 * (r.x - mr) + a11 * (i.x - mi) + b1;
    yi.y = a10 * (r.y - mr) + a11 * (i.y - mi) + b1;
    yi.z = a10 * (r.z - mr) + a11 * (i.z - mi) + b1;
    yi.w = a10 * (r.w - mr) + a11 * (i.w - mi) + b1;

    *reinterpret_cast<float4*>(out + baseR + idx) = yr;
    *reinterpret_cast<float4*>(out + baseI + idx) = yi;
}

// ---------------------------------------------------------------------------
extern "C" void kernel_launch(void* const* d_in, const int* in_sizes, int n_in,
                              void* d_out, int out_size, void* d_ws, size_t ws_size,
                              hipStream_t stream) {
    const float* x     = (const float*)d_in[0];
    const float* gamma = (const float*)d_in[1];
    const float* beta  = (const float*)d_in[2];
    float* out = (float*)d_out;

    float* part = (float*)d_ws;           // C*B*5 = 10240 floats
    float* coef = part + C * B * 5;       // 64*8  =   512 floats

    k_partial<<<dim3(C, B), 256, 0, stream>>>(x, part);
    k_stats<<<1, 64, 0, stream>>>(part, gamma, beta, coef);
    k_norm<<<dim3(HW / 1024, B * C), 256, 0, stream>>>(x, coef, out);
}

// Round 2
// 129.507 us; speedup vs baseline: 1.1916x; 1.1916x over previous
//
#include <hip/hip_runtime.h>
#include <math.h>

// Problem constants (from reference setup)
constexpr int B  = 32;
constexpr int C  = 64;
constexpr int H  = 128;
constexpr int W  = 128;
constexpr int HW = H * W;            // 16384
constexpr int SB = 2 * C * HW;       // per-batch stride in floats = 2,097,152
constexpr float EPS = 1e-5f;

typedef float v4f __attribute__((ext_vector_type(4)));

// ---------------------------------------------------------------------------
// Kernel 1: per-(channel, batch) partial sums.
// Each block reduces one 16384-element xr plane and its paired xi plane.
// Outputs 5 floats per (c,b): sum_r, sum_i, sum_rr, sum_ii, sum_ri.
// Regular (caching) loads: we WANT x resident in the Infinity Cache for the
// second pass.
// ---------------------------------------------------------------------------
__global__ __launch_bounds__(256) void k_partial(const float* __restrict__ x,
                                                 float* __restrict__ part) {
    const int c = blockIdx.x;   // channel
    const int b = blockIdx.y;   // batch
    const float* __restrict__ xr = x + (size_t)b * SB + (size_t)c * HW;
    const float* __restrict__ xi = xr + (size_t)C * HW;
    const int tid = threadIdx.x;

    float sr = 0.f, si = 0.f, srr = 0.f, sii = 0.f, sri = 0.f;

#pragma unroll
    for (int it = 0; it < HW / (256 * 4); ++it) {   // 16 iterations
        const int idx = (it * 256 + tid) * 4;
        const v4f r = *reinterpret_cast<const v4f*>(xr + idx);
        const v4f i = *reinterpret_cast<const v4f*>(xi + idx);
        sr  += r.x + r.y + r.z + r.w;
        si  += i.x + i.y + i.z + i.w;
        srr += r.x * r.x + r.y * r.y + r.z * r.z + r.w * r.w;
        sii += i.x * i.x + i.y * i.y + i.z * i.z + i.w * i.w;
        sri += r.x * i.x + r.y * i.y + r.z * i.z + r.w * i.w;
    }

    // 64-lane wave reduction
#pragma unroll
    for (int off = 32; off > 0; off >>= 1) {
        sr  += __shfl_down(sr,  off);
        si  += __shfl_down(si,  off);
        srr += __shfl_down(srr, off);
        sii += __shfl_down(sii, off);
        sri += __shfl_down(sri, off);
    }

    __shared__ float smem[4][5];
    const int wave = tid >> 6;
    const int lane = tid & 63;
    if (lane == 0) {
        smem[wave][0] = sr;  smem[wave][1] = si;  smem[wave][2] = srr;
        smem[wave][3] = sii; smem[wave][4] = sri;
    }
    __syncthreads();
    if (tid == 0) {
        float* dst = part + ((size_t)c * B + b) * 5;
#pragma unroll
        for (int k = 0; k < 5; ++k)
            dst[k] = smem[0][k] + smem[1][k] + smem[2][k] + smem[3][k];
    }
}

// ---------------------------------------------------------------------------
// Per-channel whitening coefficients, computed from the 32 partials.
// Implements the reference math LITERALLY (t = sqrt(tau + 2*delta), and
// s added to all four q entries). Called redundantly by every thread of
// every k_norm block (uniform addresses -> scalar loads, negligible cost);
// this removes the separate k_stats dispatch from the critical path.
// ---------------------------------------------------------------------------
__device__ __forceinline__ void channel_coefs(const float* __restrict__ part,
                                              const float* __restrict__ gamma,
                                              const float* __restrict__ beta,
                                              int c,
                                              float& mr, float& mi,
                                              float& a00, float& a01,
                                              float& a10, float& a11,
                                              float& b0, float& b1) {
    float sr = 0.f, si = 0.f, srr = 0.f, sii = 0.f, sri = 0.f;
    const float* p = part + (size_t)c * B * 5;
#pragma unroll
    for (int b = 0; b < B; ++b) {
        sr  += p[b * 5 + 0];
        si  += p[b * 5 + 1];
        srr += p[b * 5 + 2];
        sii += p[b * 5 + 3];
        sri += p[b * 5 + 4];
    }
    const float N    = (float)(B * HW);       // 524288
    const float invN = 1.f / N;
    mr = sr * invN;
    mi = si * invN;
    const float d = N - 1.f;

    const float covRR = (srr - N * mr * mr) / d;
    const float covII = (sii - N * mi * mi) / d;
    const float covRI = (sri - N * mr * mi) / d;

    const float m00 = covRR + EPS;
    const float m01 = covRI;
    const float m10 = covRI;
    const float m11 = covII + EPS;

    const float tau   = m00 + m11;
    const float delta = m00 * m11 - m01 * m10;
    const float s     = sqrtf(delta);
    const float t     = sqrtf(tau + 2.f * delta);   // reference: delta, not s

    const float q00 = (m00 + s) / t;
    const float q01 = (m01 + s) / t;
    const float q10 = (m10 + s) / t;
    const float q11 = (m11 + s) / t;

    const float det    = q00 * q11 - q01 * q10;
    const float invdet = 1.f / det;
    const float v00 =  q11 * invdet;
    const float v01 = -q01 * invdet;
    const float v10 = -q10 * invdet;
    const float v11 =  q00 * invdet;

    const float g00 = gamma[c * 4 + 0];
    const float g01 = gamma[c * 4 + 1];
    const float g10 = gamma[c * 4 + 2];
    const float g11 = gamma[c * 4 + 3];

    a00 = g00 * v00 + g01 * v10;
    a01 = g00 * v01 + g01 * v11;
    a10 = g10 * v00 + g11 * v10;
    a11 = g10 * v01 + g11 * v11;
    b0  = beta[c * 2 + 0];
    b1  = beta[c * 2 + 1];
}

// ---------------------------------------------------------------------------
// Kernel 2: elementwise normalize. Grid (HW/1024, B*C).
// Non-temporal loads (last use of x) and non-temporal stores (streaming
// output) so y's 268 MB doesn't evict x from the Infinity Cache while the
// second pass is still harvesting L3 hits.
// ---------------------------------------------------------------------------
__global__ __launch_bounds__(256) void k_norm(const float* __restrict__ x,
                                              const float* __restrict__ part,
                                              const float* __restrict__ gamma,
                                              const float* __restrict__ beta,
                                              float* __restrict__ out) {
    const int bc = blockIdx.y;       // 0 .. B*C-1
    const int b  = bc / C;
    const int c  = bc % C;

    float mr, mi, a00, a01, a10, a11, b0, b1;
    channel_coefs(part, gamma, beta, c, mr, mi, a00, a01, a10, a11, b0, b1);

    const size_t baseR = (size_t)b * SB + (size_t)c * HW;
    const size_t baseI = baseR + (size_t)C * HW;
    const int idx = (blockIdx.x * 256 + threadIdx.x) * 4;

    const v4f r = __builtin_nontemporal_load(
        reinterpret_cast<const v4f*>(x + baseR + idx));
    const v4f i = __builtin_nontemporal_load(
        reinterpret_cast<const v4f*>(x + baseI + idx));

    v4f yr, yi;
    yr.x = a00 * (r.x - mr) + a01 * (i.x - mi) + b0;
    yr.y = a00 * (r.y - mr) + a01 * (i.y - mi) + b0;
    yr.z = a00 * (r.z - mr) + a01 * (i.z - mi) + b0;
    yr.w = a00 * (r.w - mr) + a01 * (i.w - mi) + b0;
    yi.x = a10 * (r.x - mr) + a11 * (i.x - mi) + b1;
    yi.y = a10 * (r.y - mr) + a11 * (i.y - mi) + b1;
    yi.z = a10 * (r.z - mr) + a11 * (i.z - mi) + b1;
    yi.w = a10 * (r.w - mr) + a11 * (i.w - mi) + b1;

    __builtin_nontemporal_store(yr, reinterpret_cast<v4f*>(out + baseR + idx));
    __builtin_nontemporal_store(yi, reinterpret_cast<v4f*>(out + baseI + idx));
}

// ---------------------------------------------------------------------------
extern "C" void kernel_launch(void* const* d_in, const int* in_sizes, int n_in,
                              void* d_out, int out_size, void* d_ws, size_t ws_size,
                              hipStream_t stream) {
    const float* x     = (const float*)d_in[0];
    const float* gamma = (const float*)d_in[1];
    const float* beta  = (const float*)d_in[2];
    float* out = (float*)d_out;

    float* part = (float*)d_ws;           // C*B*5 = 10240 floats

    k_partial<<<dim3(C, B), 256, 0, stream>>>(x, part);
    k_norm<<<dim3(HW / 1024, B * C), 256, 0, stream>>>(x, part, gamma, beta, out);
}